// Round 9
// baseline (118.465 us; speedup 1.0000x reference)
//
#include <hip/hip_runtime.h>

// x:  [N=4, C=256, H=56, W=56] fp32
// w1: [N, 1, 32, 9,  H, W]     (3x3, pad 1)
// w2: [N, 1, 32, 25, H, W]     (5x5, pad 2)
// out:[N, 2, 1, C, H, W]
// out[n,b,c,h,w] = sum_p wB[n, c%32, p, h, w] * x[n, c, h+dh, w+dw] (zero pad)
//
// R16 = R15 + PRE-BARRIER WEIGHT PREFETCH-AND-DISCARD.
// Evidence: every block pays two serial cold HBM round trips: [x-stage RTT +
// barrier] then [weight-stream RTT]. R7 (prior session) preloaded weights
// into live registers across the barrier -> spilled (WRITE 62 MB). This
// version prefetches WITHOUT live state: each compute thread issues its 34
// weight float4 loads up front, folds them into one accumulator (independent
// loads cluster-issue; FIFO vmcnt waits pipeline to ~1 RTT), and discards
// the sum into the unused d_ws workspace (observable store -> no DCE; d_ws
// is scratch -> no correctness impact). Weight + x lines travel in ONE cold
// burst; post-barrier weight re-loads hit L2/L3 (~200 cyc), which the
// depth-2 pipeline fully covers.
// Everything else identical to R15/R12: TILE 14, gsel split (weight dedup
// via same-XCD L2, proven load-bearing by R10), LSTRIDE 68, 196 compute
// threads, w2 depth-2 row prefetch, all-9 early w1 loads, NT output stores.

#define N_  4
#define C_  256
#define H_  56
#define W_  56
#define HW_ 3136
#define WC_ 32

#define TILE    14
#define LROWS   18   // TILE + 4 halo rows
#define LSTRIDE 68   // x col c -> slot c+2; slots 0,1 & 58,59 zero halo

typedef float vfloat4 __attribute__((ext_vector_type(4)));

__global__ __launch_bounds__(256) void lconv_kernel(
    const float* __restrict__ x,
    const float* __restrict__ w1,
    const float* __restrict__ w2,
    float* __restrict__ out,
    float* __restrict__ ws)
{
    __shared__ float lds[4 * LROWS * LSTRIDE];   // 19584 B

    const int b     = blockIdx.x;        // 0..1023
    const int tile  = b & 3;
    const int vlow  = (b >> 2) & 1;
    const int gsel  = (b >> 3) & 1;      // stride 8 -> gsel-pair on same XCD
    const int vhigh = (b >> 4) & 15;
    const int n     = b >> 8;
    const int v     = (vhigh << 1) | vlow;
    const int r0    = tile * TILE;
    const int nv    = n * WC_ + v;
    const int tid   = threadIdx.x;

    // compute-thread geometry (hoisted: needed for prefetch)
    int row = 0, s = 0, wb = 0, h = 0, hw = 0;
    const float* w1t = nullptr;
    const float* w2t = nullptr;

    // ---- pre-barrier weight prefetch-and-discard (compute threads only) ----
    if (tid < TILE * 14) {
        row = tid / 14;                  // 0..13
        s   = tid - row * 14;
        wb  = 4 * s;                     // 0,4,...,52
        h   = r0 + row;
        hw  = h * W_ + wb;
        w1t = w1 + (size_t)nv * 9  * HW_ + hw;
        w2t = w2 + (size_t)nv * 25 * HW_ + hw;

        vfloat4 acc = {0.f, 0.f, 0.f, 0.f};
        #pragma unroll
        for (int q = 0; q < 25; ++q)
            acc += *(const vfloat4*)(w2t + (size_t)q * HW_);
        #pragma unroll
        for (int q = 0; q < 9; ++q)
            acc += *(const vfloat4*)(w1t + (size_t)q * HW_);
        // observable discard: d_ws is scratch, re-poisoned by harness
        if (ws) ws[b * 256 + tid] = acc.x + acc.y + acc.z + acc.w;
    }

    // ---- stage x: 4 planes x 18 rows x 56 cols; zero OOB rows ----
    for (int idx = tid; idx < 4 * LROWS * 14; idx += 256) {
        const int c4 = idx % 14;
        const int t2 = idx / 14;
        const int lr = t2 % LROWS;
        const int pl = t2 / LROWS;
        const int gr = r0 - 2 + lr;
        float4 val = make_float4(0.f, 0.f, 0.f, 0.f);
        if (gr >= 0 && gr < H_) {
            const int ch = gsel * 128 + pl * 32 + v;
            val = *(const float4*)(x + (size_t)(n * C_ + ch) * HW_ + gr * W_ + c4 * 4);
        }
        float* lp = &lds[(pl * LROWS + lr) * LSTRIDE + 4 * c4 + 2];
        *(float2*)(lp)     = make_float2(val.x, val.y);
        *(float2*)(lp + 2) = make_float2(val.z, val.w);
    }
    // zero column halos: slots 0,1 (x cols -2,-1) and 58,59 (x cols 56,57)
    for (int idx = tid; idx < 4 * LROWS * 4; idx += 256) {
        const int k  = idx & 3;
        const int t2 = idx >> 2;
        const int lr = t2 % LROWS;
        const int pl = t2 / LROWS;
        const int slot = (k < 2) ? k : (56 + k);
        lds[(pl * LROWS + lr) * LSTRIDE + slot] = 0.f;
    }
    __syncthreads();

    if (tid >= TILE * 14) return;        // 196 compute threads; no barriers below

    const int c0 = gsel * 128 + v;

    // ================= 5x5 branch: depth-2 row pipeline, full unroll ======
    float a2[4][4];
    #pragma unroll
    for (int g = 0; g < 4; ++g)
        #pragma unroll
        for (int p = 0; p < 4; ++p) a2[g][p] = 0.f;

    float4 w2r[5][5];                    // [di][dj], fully static-indexed
    #pragma unroll
    for (int dj = 0; dj < 5; ++dj)
        w2r[0][dj] = *(const float4*)(w2t + (size_t)dj * HW_);
    #pragma unroll
    for (int dj = 0; dj < 5; ++dj)
        w2r[1][dj] = *(const float4*)(w2t + (size_t)(5 + dj) * HW_);

    // w1 loads issued here: they complete during the whole 5x5 phase
    float4 w1r[9];
    #pragma unroll
    for (int q = 0; q < 9; ++q)
        w1r[q] = *(const float4*)(w1t + (size_t)q * HW_);

    #pragma unroll
    for (int di = 0; di < 5; ++di) {
        if (di + 2 < 5) {                // prefetch row di+2, used 2 iters later
            #pragma unroll
            for (int dj = 0; dj < 5; ++dj)
                w2r[di + 2][dj] = *(const float4*)(w2t + (size_t)((di + 2) * 5 + dj) * HW_);
        }
        #pragma unroll
        for (int g = 0; g < 4; ++g) {
            const float* lp = &lds[(g * LROWS + row + di) * LSTRIDE + wb];
            const float4 xa  = *(const float4*)(lp);
            const float4 xb4 = *(const float4*)(lp + 4);
            const float xw[8] = {xa.x, xa.y, xa.z, xa.w, xb4.x, xb4.y, xb4.z, xb4.w};
            #pragma unroll
            for (int dj = 0; dj < 5; ++dj) {
                const float* wr = (const float*)&w2r[di][dj];
                #pragma unroll
                for (int p = 0; p < 4; ++p)
                    a2[g][p] += wr[p] * xw[p + dj];
            }
        }
    }

    float* o2 = out + ((size_t)(n * 2 + 1) * C_ + c0) * HW_ + hw;
    #pragma unroll
    for (int g = 0; g < 4; ++g) {
        vfloat4 sv = {a2[g][0], a2[g][1], a2[g][2], a2[g][3]};
        __builtin_nontemporal_store(sv, (vfloat4*)(o2 + (size_t)g * WC_ * HW_));
    }

    // ================= 3x3 branch: weights already in registers ===========
    float a1[4][4];
    #pragma unroll
    for (int g = 0; g < 4; ++g)
        #pragma unroll
        for (int p = 0; p < 4; ++p) a1[g][p] = 0.f;

    #pragma unroll
    for (int di = 0; di < 3; ++di) {
        #pragma unroll
        for (int g = 0; g < 4; ++g) {
            // x rows h-1+di -> LDS row row+1+di
            const float* lp = &lds[(g * LROWS + row + 1 + di) * LSTRIDE + wb];
            const float4 xa  = *(const float4*)(lp);
            const float4 xb4 = *(const float4*)(lp + 4);
            const float xw[8] = {xa.x, xa.y, xa.z, xa.w, xb4.x, xb4.y, xb4.z, xb4.w};
            #pragma unroll
            for (int dj = 0; dj < 3; ++dj) {
                const float* wr = (const float*)&w1r[di * 3 + dj];
                #pragma unroll
                for (int p = 0; p < 4; ++p)
                    a1[g][p] += wr[p] * xw[p + dj + 1];
            }
        }
    }

    float* o1 = out + ((size_t)(n * 2 + 0) * C_ + c0) * HW_ + hw;
    #pragma unroll
    for (int g = 0; g < 4; ++g) {
        vfloat4 sv = {a1[g][0], a1[g][1], a1[g][2], a1[g][3]};
        __builtin_nontemporal_store(sv, (vfloat4*)(o1 + (size_t)g * WC_ * HW_));
    }
}

extern "C" void kernel_launch(void* const* d_in, const int* in_sizes, int n_in,
                              void* d_out, int out_size, void* d_ws, size_t ws_size,
                              hipStream_t stream) {
    const float* x  = (const float*)d_in[0];
    const float* w1 = (const float*)d_in[1];
    const float* w2 = (const float*)d_in[2];
    float* out = (float*)d_out;
    float* ws  = (ws_size >= (size_t)1024 * 256 * sizeof(float)) ? (float*)d_ws : nullptr;

    dim3 grid(1024), block(256);   // 4 blocks/CU
    hipLaunchKernelGGL(lconv_kernel, grid, block, 0, stream, x, w1, w2, out, ws);
}

// Round 12
// 113.672 us; speedup vs baseline: 1.0422x; 1.0422x over previous
//
#include <hip/hip_runtime.h>

// x:  [N=4, C=256, H=56, W=56] fp32
// w1: [N, 1, 32, 9,  H, W]     (3x3, pad 1)
// w2: [N, 1, 32, 25, H, W]     (5x5, pad 2)
// out:[N, 2, 1, C, H, W]
// out[n,b,c,h,w] = sum_p wB[n, c%32, p, h, w] * x[n, c, h+dh, w+dw] (zero pad)
//
// R19 = R12 + PRE-BARRIER REGISTER PRELOAD of w2 rows 0-1 and all of w1
// (19 taps = 76 VGPR), issued BEFORE the x-staging loop.
// Evidence chain:
//  - R17/R18 (counted-vmcnt global_load_lds ring, no barrier) failed absmax
//    ~10 twice -> barrier-less DMA-consume semantics unverified; abandoned.
//  - Gap model: kernel 29.3us vs ~19us floor = per-row weight-wait exposure
//    x 2 residency rounds. Registers are the only verified landing buffer.
//  - R7 preloaded ALL 34 taps -> 136 live regs -> spill. 19 taps = 76 regs,
//    issued before staging (disjoint live sets): pre-barrier peak ~120 <
//    R12's post-barrier 188 peak -> no allocator squeeze, same occupancy.
//  - Effect: weight cold-start RTT overlaps x-staging RTT (one burst, not
//    serial); di=0 compute starts at barrier-exit with rows 0-1 hot; rows
//    2-4 keep R12's depth-2 issue, now covered by di=0-1 compute.
// Falsification: VGPR>220 or WRITE>26MB = spill; flat time = latency
// structure conserved -> practical roofline.

#define N_  4
#define C_  256
#define H_  56
#define W_  56
#define HW_ 3136
#define WC_ 32

#define TILE    14
#define LROWS   18   // TILE + 4 halo rows
#define LSTRIDE 68   // x col c -> slot c+2; slots 0,1 & 58,59 zero halo

typedef float vfloat4 __attribute__((ext_vector_type(4)));

__global__ __launch_bounds__(256) void lconv_kernel(
    const float* __restrict__ x,
    const float* __restrict__ w1,
    const float* __restrict__ w2,
    float* __restrict__ out)
{
    __shared__ float lds[4 * LROWS * LSTRIDE];   // 19584 B

    const int b     = blockIdx.x;        // 0..1023
    const int tile  = b & 3;
    const int vlow  = (b >> 2) & 1;
    const int gsel  = (b >> 3) & 1;      // stride 8 -> gsel-pair on same XCD
    const int vhigh = (b >> 4) & 15;
    const int n     = b >> 8;
    const int v     = (vhigh << 1) | vlow;
    const int r0    = tile * TILE;
    const int nv    = n * WC_ + v;
    const int tid   = threadIdx.x;

    // ---- geometry + PRE-BARRIER weight preload (compute threads only) ----
    int row = 0, s = 0, wb = 0, h = 0, hw = 0;
    const float* w1t = nullptr;
    const float* w2t = nullptr;
    float4 w2r[5][5];                    // rows 0,1 filled pre-barrier
    float4 w1r[9];                       // all filled pre-barrier

    if (tid < TILE * 14) {
        row = tid / 14;                  // 0..13
        s   = tid - row * 14;
        wb  = 4 * s;                     // 0,4,...,52
        h   = r0 + row;
        hw  = h * W_ + wb;
        w1t = w1 + (size_t)nv * 9  * HW_ + hw;
        w2t = w2 + (size_t)nv * 25 * HW_ + hw;

        // 19 independent loads, issued before any staging load: their HBM
        // RTT overlaps the x-stage RTT; values land by the barrier drain.
        #pragma unroll
        for (int dj = 0; dj < 5; ++dj)
            w2r[0][dj] = *(const float4*)(w2t + (size_t)dj * HW_);
        #pragma unroll
        for (int dj = 0; dj < 5; ++dj)
            w2r[1][dj] = *(const float4*)(w2t + (size_t)(5 + dj) * HW_);
        #pragma unroll
        for (int q = 0; q < 9; ++q)
            w1r[q] = *(const float4*)(w1t + (size_t)q * HW_);
    }

    // ---- stage x: 4 planes x 18 rows x 56 cols; zero OOB rows ----
    for (int idx = tid; idx < 4 * LROWS * 14; idx += 256) {
        const int c4 = idx % 14;
        const int t2 = idx / 14;
        const int lr = t2 % LROWS;
        const int pl = t2 / LROWS;
        const int gr = r0 - 2 + lr;
        float4 val = make_float4(0.f, 0.f, 0.f, 0.f);
        if (gr >= 0 && gr < H_) {
            const int ch = gsel * 128 + pl * 32 + v;
            val = *(const float4*)(x + (size_t)(n * C_ + ch) * HW_ + gr * W_ + c4 * 4);
        }
        float* lp = &lds[(pl * LROWS + lr) * LSTRIDE + 4 * c4 + 2];
        *(float2*)(lp)     = make_float2(val.x, val.y);
        *(float2*)(lp + 2) = make_float2(val.z, val.w);
    }
    // zero column halos: slots 0,1 (x cols -2,-1) and 58,59 (x cols 56,57)
    for (int idx = tid; idx < 4 * LROWS * 4; idx += 256) {
        const int k  = idx & 3;
        const int t2 = idx >> 2;
        const int lr = t2 % LROWS;
        const int pl = t2 / LROWS;
        const int slot = (k < 2) ? k : (56 + k);
        lds[(pl * LROWS + lr) * LSTRIDE + slot] = 0.f;
    }
    __syncthreads();                     // drains vmcnt(0): preloads landed

    if (tid >= TILE * 14) return;        // 196 compute threads; no barriers below

    const int c0 = gsel * 128 + v;

    // ================= 5x5 branch: rows 0-1 hot, depth-2 for rows 2-4 =====
    float a2[4][4];
    #pragma unroll
    for (int g = 0; g < 4; ++g)
        #pragma unroll
        for (int p = 0; p < 4; ++p) a2[g][p] = 0.f;

    #pragma unroll
    for (int di = 0; di < 5; ++di) {
        if (di + 2 < 5) {                // issue row di+2, used 2 iters later
            #pragma unroll
            for (int dj = 0; dj < 5; ++dj)
                w2r[di + 2][dj] = *(const float4*)(w2t + (size_t)((di + 2) * 5 + dj) * HW_);
        }
        #pragma unroll
        for (int g = 0; g < 4; ++g) {
            const float* lp = &lds[(g * LROWS + row + di) * LSTRIDE + wb];
            const float4 xa  = *(const float4*)(lp);
            const float4 xb4 = *(const float4*)(lp + 4);
            const float xw[8] = {xa.x, xa.y, xa.z, xa.w, xb4.x, xb4.y, xb4.z, xb4.w};
            #pragma unroll
            for (int dj = 0; dj < 5; ++dj) {
                const float* wr = (const float*)&w2r[di][dj];
                #pragma unroll
                for (int p = 0; p < 4; ++p)
                    a2[g][p] += wr[p] * xw[p + dj];
            }
        }
    }

    float* o2 = out + ((size_t)(n * 2 + 1) * C_ + c0) * HW_ + hw;
    #pragma unroll
    for (int g = 0; g < 4; ++g) {
        vfloat4 sv = {a2[g][0], a2[g][1], a2[g][2], a2[g][3]};
        __builtin_nontemporal_store(sv, (vfloat4*)(o2 + (size_t)g * WC_ * HW_));
    }

    // ================= 3x3 branch: weights preloaded pre-barrier ==========
    float a1[4][4];
    #pragma unroll
    for (int g = 0; g < 4; ++g)
        #pragma unroll
        for (int p = 0; p < 4; ++p) a1[g][p] = 0.f;

    #pragma unroll
    for (int di = 0; di < 3; ++di) {
        #pragma unroll
        for (int g = 0; g < 4; ++g) {
            // x rows h-1+di -> LDS row row+1+di
            const float* lp = &lds[(g * LROWS + row + 1 + di) * LSTRIDE + wb];
            const float4 xa  = *(const float4*)(lp);
            const float4 xb4 = *(const float4*)(lp + 4);
            const float xw[8] = {xa.x, xa.y, xa.z, xa.w, xb4.x, xb4.y, xb4.z, xb4.w};
            #pragma unroll
            for (int dj = 0; dj < 3; ++dj) {
                const float* wr = (const float*)&w1r[di * 3 + dj];
                #pragma unroll
                for (int p = 0; p < 4; ++p)
                    a1[g][p] += wr[p] * xw[p + dj + 1];
            }
        }
    }

    float* o1 = out + ((size_t)(n * 2 + 0) * C_ + c0) * HW_ + hw;
    #pragma unroll
    for (int g = 0; g < 4; ++g) {
        vfloat4 sv = {a1[g][0], a1[g][1], a1[g][2], a1[g][3]};
        __builtin_nontemporal_store(sv, (vfloat4*)(o1 + (size_t)g * WC_ * HW_));
    }
}

extern "C" void kernel_launch(void* const* d_in, const int* in_sizes, int n_in,
                              void* d_out, int out_size, void* d_ws, size_t ws_size,
                              hipStream_t stream) {
    const float* x  = (const float*)d_in[0];
    const float* w1 = (const float*)d_in[1];
    const float* w2 = (const float*)d_in[2];
    float* out = (float*)d_out;

    dim3 grid(1024), block(256);
    hipLaunchKernelGGL(lconv_kernel, grid, block, 0, stream, x, w1, w2, out);
}